// Round 4
// baseline (277.995 us; speedup 1.0000x reference)
//
#include <hip/hip_runtime.h>
#include <stdint.h>

#define B_ 8
#define H_ 128
#define W_ 128
#define D_ 128
#define N_ (H_*W_)
#define M_ (B_*N_)   // 131072 rows total

typedef __attribute__((ext_vector_type(8))) short short8;
typedef __attribute__((ext_vector_type(4))) float floatx4;

typedef const __attribute__((address_space(1))) void* gas_t;
typedef __attribute__((address_space(3))) void* las_t;

__device__ inline unsigned short f2bf(float f){
  union { float f; unsigned int i; } c; c.f = f;
  unsigned int x = c.i;
  x += 0x7FFF + ((x >> 16) & 1);   // RNE
  return (unsigned short)(x >> 16);
}
__device__ inline float bflo(unsigned int u){
  union { unsigned int i; float f; } c; c.i = u << 16; return c.f;
}
__device__ inline float bfhi(unsigned int u){
  union { unsigned int i; float f; } c; c.i = u & 0xFFFF0000u; return c.f;
}

// ---------------- kernel 0: W -> W^T bf16, 192 blocks ----------------
__global__ void wtrans_kernel(const float* __restrict__ Wq, const float* __restrict__ Wk,
                              const float* __restrict__ Wv, unsigned short* __restrict__ Wt){
  const float* src = blockIdx.x == 0 ? Wq : (blockIdx.x == 1 ? Wk : Wv);
  unsigned short* dst = Wt + blockIdx.x * (D_*D_);
  const int i = blockIdx.y * 256 + threadIdx.x;
  const int k = i >> 7, n = i & 127;
  dst[n*D_ + k] = f2bf(src[i]);
}

// ---------------- kernel 1: QKV projection, bf16 MFMA 128x128 tile (unchanged r3) ----
__global__ __launch_bounds__(256, 2) void qkv_gemm_kernel(
    const float* __restrict__ x, const unsigned short* __restrict__ Wt,
    const float* __restrict__ bq, const float* __restrict__ bk, const float* __restrict__ bv,
    unsigned short* __restrict__ Q, unsigned short* __restrict__ K, unsigned short* __restrict__ V)
{
  const int which = blockIdx.x;          // 0=Q 1=K 2=V
  const int rowTile = blockIdx.y;
  const float* bias = which == 0 ? bq : (which == 1 ? bk : bv);
  unsigned short* Out = which == 0 ? Q : (which == 1 ? K : V);
  const unsigned short* Wsel = Wt + which * (D_*D_);

  __shared__ unsigned short lds[32768];  // 64 KB -> 2 blocks/CU

  const int t = threadIdx.x;
  const int wave = t >> 6, lane = t & 63;

  // ---- B stage: async global->LDS, 16B/lane
  {
    #pragma unroll
    for (int p = 0; p < 8; ++p){
      int s = p*256 + t;
      int n = s >> 4, cp = s & 15, c = cp ^ (n & 7);
      const unsigned short* gp = Wsel + n*128 + c*8;
      unsigned short* lp = (unsigned short*)lds + 16384 + p*2048 + wave*512;
      __builtin_amdgcn_global_load_lds((gas_t)(const void*)gp, (las_t)(void*)lp, 16, 0, 0);
    }
  }
  // ---- A stage: fp32 x -> bf16, swizzled ds_write_b128
  {
    const float* xrow = x + (size_t)rowTile * 128 * D_;
    #pragma unroll
    for (int p = 0; p < 8; ++p){
      int s = p*256 + t;
      int r = s >> 4, cp = s & 15, c = cp ^ (r & 7);
      const float* gp = xrow + r*D_ + c*8;
      float4 f0 = *(const float4*)gp;
      float4 f1 = *(const float4*)(gp + 4);
      uint4 pk;
      pk.x = (unsigned)f2bf(f0.x) | ((unsigned)f2bf(f0.y) << 16);
      pk.y = (unsigned)f2bf(f0.z) | ((unsigned)f2bf(f0.w) << 16);
      pk.z = (unsigned)f2bf(f1.x) | ((unsigned)f2bf(f1.y) << 16);
      pk.w = (unsigned)f2bf(f1.z) | ((unsigned)f2bf(f1.w) << 16);
      *(uint4*)&lds[s*8] = pk;
    }
  }
  __syncthreads();

  const int wm = (wave >> 1) * 64, wn = (wave & 1) * 64;
  const int m0 = lane & 15, quad = lane >> 4;

  floatx4 acc[4][4] = {};
  #pragma unroll
  for (int kk = 0; kk < 4; ++kk){
    short8 a[4], b[4];
    #pragma unroll
    for (int i = 0; i < 4; ++i){
      int row = wm + i*16 + m0;
      int c = (kk*4 + quad) ^ (row & 7);
      a[i] = *(const short8*)&lds[row*128 + c*8];
    }
    #pragma unroll
    for (int j = 0; j < 4; ++j){
      int n = wn + j*16 + m0;
      int c = (kk*4 + quad) ^ (n & 7);
      b[j] = *(const short8*)&lds[16384 + n*128 + c*8];
    }
    #pragma unroll
    for (int i = 0; i < 4; ++i)
      #pragma unroll
      for (int j = 0; j < 4; ++j)
        acc[i][j] = __builtin_amdgcn_mfma_f32_16x16x32_bf16(a[i], b[j], acc[i][j], 0, 0, 0);
  }

  __syncthreads();
  #pragma unroll
  for (int j = 0; j < 4; ++j){
    const int col = wn + j*16 + m0;
    const float bb = bias[col];
    #pragma unroll
    for (int i = 0; i < 4; ++i){
      #pragma unroll
      for (int r = 0; r < 4; ++r){
        int row = wm + i*16 + quad*4 + r;   // C/D: col=lane&15, row=quad*4+reg
        lds[row*136 + col] = f2bf(acc[i][j][r] + bb);
      }
    }
  }
  __syncthreads();
  unsigned short* Outp = Out + (size_t)rowTile * 128 * D_;
  #pragma unroll
  for (int p = 0; p < 8; ++p){
    int rr = p*16 + (t >> 4), cc = t & 15;
    uint4 v = *(const uint4*)&lds[rr*136 + cc*8];
    *(uint4*)(Outp + p*2048 + t*8) = v;
  }
}

// ---------------- kernel 2: 3x3 window attention, LDS-staged K/V tile+halo ----------
// Block = 8x8 pixel tile, 4 threads/pixel (32 dims each). Halo 10x10 rows staged in
// one 26.8 KB LDS buffer, reused K then V (5 blocks/CU). Zero-filled OOB rows
// reproduce the reference's zero-padding -> NO bounds checks in compute.
// Row stride 134 ushorts (67 words, odd) -> compute ds_read_b128 <=2-way (free).
#define SR_ 134
__global__ __launch_bounds__(256) void attn_kernel(
    const unsigned short* __restrict__ Q, const unsigned short* __restrict__ K,
    const unsigned short* __restrict__ V, float* __restrict__ out)
{
  __shared__ unsigned short sh[100 * SR_];

  const int t  = threadIdx.x;
  const int bx = blockIdx.x;        // tile x: 0..15
  const int by = blockIdx.y;        // tile y: 0..15
  const int bz = blockIdx.z;        // batch : 0..7
  const int gx0 = bx*8 - 1, gy0 = by*8 - 1;

  // ---- stage K halo (100 rows x 128 ushorts = 1600 16B-chunks) ----
  #pragma unroll
  for (int p = 0; p < 7; ++p){
    int s = p*256 + t;
    if (s < 1600){
      int r = s >> 4, c = s & 15;
      int ly = r / 10, lx = r - ly*10;
      int py = gy0 + ly, px = gx0 + lx;
      uint4 val = make_uint4(0,0,0,0);
      if (((unsigned)py < 128u) && ((unsigned)px < 128u)){
        size_t pix = ((size_t)bz*N_ + py*W_ + px);
        val = *(const uint4*)(K + pix*D_ + c*8);
      }
      *(uint4*)&sh[r*SR_ + c*8] = val;
    }
  }

  // ---- load q (own pixel, own 32-dim quarter), pre-scaled ----
  const int quarter = t & 3;
  const int pi = t >> 2;            // 0..63
  const int ty = pi >> 3, tx = pi & 7;
  const size_t mypix = (size_t)bz*N_ + (by*8 + ty)*W_ + (bx*8 + tx);
  const size_t off = mypix*D_ + quarter*32;
  const float scale = 0.08838834764831845f; // 1/sqrt(128)

  float q[32];
  {
    const unsigned short* qp = Q + off;
    #pragma unroll
    for (int c = 0; c < 4; ++c){
      uint4 u = *(const uint4*)(qp + c*8);
      unsigned uu[4] = {u.x, u.y, u.z, u.w};
      #pragma unroll
      for (int e = 0; e < 4; ++e){
        q[c*8 + e*2]     = bflo(uu[e]) * scale;
        q[c*8 + e*2 + 1] = bfhi(uu[e]) * scale;
      }
    }
  }
  __syncthreads();

  // ---- scores: 9 neighbors from LDS, no bounds checks ----
  float s9[9];
  #pragma unroll
  for (int i = 0; i < 9; ++i){
    const int dy = i/3, dx = i%3;                    // halo-space offsets
    const int lr = (ty + dy)*10 + (tx + dx);
    const unsigned short* kp = &sh[lr*SR_ + quarter*32];
    float acc = 0.f;
    #pragma unroll
    for (int c = 0; c < 4; ++c){
      uint4 u = *(const uint4*)(kp + c*8);
      unsigned uu[4] = {u.x, u.y, u.z, u.w};
      #pragma unroll
      for (int e = 0; e < 4; ++e){
        acc += q[c*8 + e*2]     * bflo(uu[e]);
        acc += q[c*8 + e*2 + 1] * bfhi(uu[e]);
      }
    }
    s9[i] = acc;
  }
  #pragma unroll
  for (int i = 0; i < 9; ++i){
    s9[i] += __shfl_xor(s9[i], 1, 64);
    s9[i] += __shfl_xor(s9[i], 2, 64);
  }

  float m = s9[0];
  #pragma unroll
  for (int i = 1; i < 9; ++i) m = fmaxf(m, s9[i]);
  float p9[9]; float l = 0.f;
  #pragma unroll
  for (int i = 0; i < 9; ++i){ p9[i] = __expf(s9[i] - m); l += p9[i]; }
  const float inv = 1.f / l;

  // ---- restage buffer with V (all K reads done) ----
  __syncthreads();
  #pragma unroll
  for (int p = 0; p < 7; ++p){
    int s = p*256 + t;
    if (s < 1600){
      int r = s >> 4, c = s & 15;
      int ly = r / 10, lx = r - ly*10;
      int py = gy0 + ly, px = gx0 + lx;
      uint4 val = make_uint4(0,0,0,0);
      if (((unsigned)py < 128u) && ((unsigned)px < 128u)){
        size_t pix = ((size_t)bz*N_ + py*W_ + px);
        val = *(const uint4*)(V + pix*D_ + c*8);
      }
      *(uint4*)&sh[r*SR_ + c*8] = val;
    }
  }
  __syncthreads();

  // ---- PV accumulation from LDS ----
  float o[32];
  #pragma unroll
  for (int d = 0; d < 32; ++d) o[d] = 0.f;
  #pragma unroll
  for (int i = 0; i < 9; ++i){
    const int dy = i/3, dx = i%3;
    const int lr = (ty + dy)*10 + (tx + dx);
    const unsigned short* vp = &sh[lr*SR_ + quarter*32];
    const float pi9 = p9[i];
    #pragma unroll
    for (int c = 0; c < 4; ++c){
      uint4 u = *(const uint4*)(vp + c*8);
      unsigned uu[4] = {u.x, u.y, u.z, u.w};
      #pragma unroll
      for (int e = 0; e < 4; ++e){
        o[c*8 + e*2]     += pi9 * bflo(uu[e]);
        o[c*8 + e*2 + 1] += pi9 * bfhi(uu[e]);
      }
    }
  }

  float* op = out + off;
  #pragma unroll
  for (int c = 0; c < 8; ++c){
    float4 v4 = make_float4(o[c*4]*inv, o[c*4+1]*inv, o[c*4+2]*inv, o[c*4+3]*inv);
    *(float4*)(op + c*4) = v4;
  }
}

extern "C" void kernel_launch(void* const* d_in, const int* in_sizes, int n_in,
                              void* d_out, int out_size, void* d_ws, size_t ws_size,
                              hipStream_t stream)
{
  const float* x  = (const float*)d_in[0];
  const float* Wq = (const float*)d_in[1];
  const float* bq = (const float*)d_in[2];
  const float* Wk = (const float*)d_in[3];
  const float* bk = (const float*)d_in[4];
  const float* Wv = (const float*)d_in[5];
  const float* bv = (const float*)d_in[6];
  float* out = (float*)d_out;

  char* ws = (char*)d_ws;
  unsigned short* Wt = (unsigned short*)ws;                                   // 96 KB
  unsigned short* Q  = (unsigned short*)(ws + (1<<17));
  unsigned short* K  = (unsigned short*)(ws + (1<<17) + (size_t)M_*D_*2);
  unsigned short* V  = (unsigned short*)(ws + (1<<17) + (size_t)2*M_*D_*2);   // ~96.1 MB

  hipLaunchKernelGGL(wtrans_kernel, dim3(3, 64), dim3(256), 0, stream, Wq, Wk, Wv, Wt);
  hipLaunchKernelGGL(qkv_gemm_kernel, dim3(3, M_/128), dim3(256), 0, stream,
                     x, Wt, bq, bk, bv, Q, K, V);
  hipLaunchKernelGGL(attn_kernel, dim3(16, 16, B_), dim3(256), 0, stream, Q, K, V, out);
}